// Round 1
// baseline (648.377 us; speedup 1.0000x reference)
//
#include <hip/hip_runtime.h>

#define NN 50000
#define EE 800000
#define LL 3
#define HH 4
#define CC 16
#define DD 64
#define GG 512
#define GRAPH_DIM 128

// ---------------------------------------------------------------------------
// utility: zero int / float ranges
// ---------------------------------------------------------------------------
__global__ void zero_i32(int* p, int n) {
    int i = blockIdx.x * blockDim.x + threadIdx.x;
    if (i < n) p[i] = 0;
}
__global__ void zero_f32(float* p, int n) {
    int i = blockIdx.x * blockDim.x + threadIdx.x;
    if (i < n) p[i] = 0.f;
}

// ---------------------------------------------------------------------------
// CSR build: histogram of dst, exclusive scan, scatter (src, attr) by dst
// ---------------------------------------------------------------------------
__global__ void hist_kernel(const int* __restrict__ dst, int* __restrict__ counts) {
    int e = blockIdx.x * blockDim.x + threadIdx.x;
    if (e < EE) atomicAdd(&counts[dst[e]], 1);
}

__global__ __launch_bounds__(1024) void scan_kernel(const int* __restrict__ counts,
                                                    int* __restrict__ row_ptr,
                                                    int* __restrict__ writepos) {
    __shared__ int wsum[16];
    int t = threadIdx.x, lane = t & 63, wid = t >> 6;
    int base = 0;
    for (int start = 0; start < NN; start += 1024) {
        int idx = start + t;
        int val = (idx < NN) ? counts[idx] : 0;
        int x = val;
        #pragma unroll
        for (int o = 1; o < 64; o <<= 1) {
            int y = __shfl_up(x, o);
            if (lane >= o) x += y;
        }
        if (lane == 63) wsum[wid] = x;
        __syncthreads();
        if (wid == 0) {
            int s = (lane < 16) ? wsum[lane] : 0;
            #pragma unroll
            for (int o = 1; o < 16; o <<= 1) {
                int y = __shfl_up(s, o);
                if (lane >= o) s += y;
            }
            if (lane < 16) wsum[lane] = s;
        }
        __syncthreads();
        int excl = x - val + base + (wid > 0 ? wsum[wid - 1] : 0);
        if (idx < NN) { row_ptr[idx] = excl; writepos[idx] = excl; }
        int total = wsum[15];
        __syncthreads();
        base += total;
    }
    if (t == 0) row_ptr[NN] = base;
}

__global__ void scatter_kernel(const int* __restrict__ ei, const float* __restrict__ attr,
                               int* __restrict__ writepos,
                               int* __restrict__ src_s, float* __restrict__ attr_s) {
    int e = blockIdx.x * blockDim.x + threadIdx.x;
    if (e < EE) {
        int s = ei[e];
        int d = ei[EE + e];
        int p = atomicAdd(&writepos[d], 1);
        src_s[p] = s;
        attr_s[p] = attr[e];
    }
}

// ---------------------------------------------------------------------------
// fused node GEMM: q = h@Wq+bq ; kv[node][0:64] = h@Wk+bk ; kv[node][64:128]
// = h@Wv+bv ; sk = h@Ws+bs.  k and v interleaved per node so node_attn can
// gather both with one address register (+256B immediate offset).
// ---------------------------------------------------------------------------
__global__ __launch_bounds__(256) void node_gemm(
    const float* __restrict__ hx,
    const float* __restrict__ Wq, const float* __restrict__ bq,
    const float* __restrict__ Wk, const float* __restrict__ bk,
    const float* __restrict__ Wv, const float* __restrict__ bv,
    const float* __restrict__ Ws, const float* __restrict__ bs,
    float* __restrict__ q, float* __restrict__ kv, float* __restrict__ sk)
{
    __shared__ float xs[32 * 64];
    int t = threadIdx.x;
    int node0 = blockIdx.x * 32;

    const float4* src4 = (const float4*)(hx + (size_t)node0 * 64);
    float4* dst4 = (float4*)xs;
    #pragma unroll
    for (int r = 0; r < 2; ++r) {
        int i4 = t + r * 256;
        int node = node0 + (i4 >> 4);
        float4 val = make_float4(0.f, 0.f, 0.f, 0.f);
        if (node < NN) val = src4[i4];
        dst4[i4] = val;
    }
    __syncthreads();

    int mat = t >> 6, j = t & 63;
    const float* W = (mat == 0) ? Wq : (mat == 1) ? Wk : (mat == 2) ? Wv : Ws;
    const float* B = (mat == 0) ? bq : (mat == 1) ? bk : (mat == 2) ? bv : bs;
    float* O       = (mat == 0) ? q  : (mat == 3) ? sk : kv;
    int stride     = (mat == 1 || mat == 2) ? 128 : 64;
    int off        = (mat == 2) ? (64 + j) : j;

    float wcol[64];
    #pragma unroll
    for (int i = 0; i < 64; ++i) wcol[i] = W[i * 64 + j];
    float bj = B[j];

    for (int n = 0; n < 32; ++n) {
        int node = node0 + n;
        if (node >= NN) break;
        float acc = bj;
        const float4* xr = (const float4*)(xs + n * 64);
        #pragma unroll
        for (int i4 = 0; i4 < 16; ++i4) {
            float4 xv = xr[i4];
            acc = fmaf(xv.x, wcol[4 * i4 + 0], acc);
            acc = fmaf(xv.y, wcol[4 * i4 + 1], acc);
            acc = fmaf(xv.z, wcol[4 * i4 + 2], acc);
            acc = fmaf(xv.w, wcol[4 * i4 + 3], acc);
        }
        O[(size_t)node * stride + off] = acc;
    }
}

// ---------------------------------------------------------------------------
// node-centric attention, float4-per-lane layout:
//   lane = slot(2b) * 16 + g16(4b);  lane owns channels [4*g16, 4*g16+3] of
//   edge slot `slot`.  One dwordx4 gather loads 4 edges' k (1KB/wave-instr);
//   v rides the same address register at +256B.  Per-head dot needs only
//   xor-1,2 shuffles; cross-slot combine (xor 16,32) hoisted out of the loop.
//   8-edge unroll: 4 dwordx4 gathers in flight per iteration.
// Algebra hoisted:  score = (q.k + a*(q.we))/4 ; sum ex*(v+a*we)
//                   = sum(ex*v) + we*sum(ex*a)
// ---------------------------------------------------------------------------
__global__ __launch_bounds__(256) void node_attn(
    const float* __restrict__ q, const float* __restrict__ kv,
    const float* __restrict__ sk,
    const float* __restrict__ We,
    const int* __restrict__ row_ptr, const int* __restrict__ src_s,
    const float* __restrict__ attr_s,
    float* __restrict__ out, int do_relu, int do_pool,
    const int* __restrict__ batch,
    float* __restrict__ gsum, float* __restrict__ gcnt)
{
    int node = blockIdx.x * 4 + (threadIdx.x >> 6);
    int lane = threadIdx.x & 63;
    if (node >= NN) return;

    int g16  = lane & 15;   // float4 channel group
    int slot = lane >> 4;   // edge slot 0..3

    size_t nb = (size_t)node * 64;
    float4 qv  = *(const float4*)(q  + nb + g16 * 4);
    float4 wev = *(const float4*)(We + g16 * 4);

    // per-head dot q.we  (head h = g16>>2 spans lanes 4h..4h+3 of each 16-group)
    float qw = fmaf(qv.x, wev.x, fmaf(qv.y, wev.y, fmaf(qv.z, wev.z, qv.w * wev.w)));
    qw += __shfl_xor(qw, 1);
    qw += __shfl_xor(qw, 2);

    int p0 = row_ptr[node];
    int p1 = row_ptr[node + 1];

    float4 acc = make_float4(0.f, 0.f, 0.f, 0.f);
    float den = 0.f, saw = 0.f;

    const float* kvg = kv + g16 * 4;

    for (int p = p0; p < p1; p += 8) {
        int e0 = p + slot;
        int e1 = p + 4 + slot;
        int i0 = min(e0, p1 - 1);
        int i1 = min(e1, p1 - 1);
        int s0 = src_s[i0];
        int s1 = src_s[i1];
        float a0 = attr_s[i0];
        float a1 = attr_s[i1];
        const float* b0p = kvg + (size_t)s0 * 128;
        const float* b1p = kvg + (size_t)s1 * 128;
        float4 k0 = *(const float4*)(b0p);
        float4 v0 = *(const float4*)(b0p + 64);   // +256B immediate
        float4 k1 = *(const float4*)(b1p);
        float4 v1 = *(const float4*)(b1p + 64);

        float r0 = fmaf(qv.x, k0.x, fmaf(qv.y, k0.y, fmaf(qv.z, k0.z, qv.w * k0.w)));
        float r1 = fmaf(qv.x, k1.x, fmaf(qv.y, k1.y, fmaf(qv.z, k1.z, qv.w * k1.w)));
        r0 += __shfl_xor(r0, 1); r1 += __shfl_xor(r1, 1);
        r0 += __shfl_xor(r0, 2); r1 += __shfl_xor(r1, 2);

        float ex0 = __expf(fmaf(a0, qw, r0) * 0.25f);
        float ex1 = __expf(fmaf(a1, qw, r1) * 0.25f);
        if (e0 >= p1) ex0 = 0.f;
        if (e1 >= p1) ex1 = 0.f;

        acc.x = fmaf(ex0, v0.x, acc.x); acc.y = fmaf(ex0, v0.y, acc.y);
        acc.z = fmaf(ex0, v0.z, acc.z); acc.w = fmaf(ex0, v0.w, acc.w);
        acc.x = fmaf(ex1, v1.x, acc.x); acc.y = fmaf(ex1, v1.y, acc.y);
        acc.z = fmaf(ex1, v1.z, acc.z); acc.w = fmaf(ex1, v1.w, acc.w);
        den += ex0 + ex1;
        saw = fmaf(ex0, a0, saw);
        saw = fmaf(ex1, a1, saw);
    }

    // combine the 4 edge slots (once per node)
    acc.x += __shfl_xor(acc.x, 16); acc.x += __shfl_xor(acc.x, 32);
    acc.y += __shfl_xor(acc.y, 16); acc.y += __shfl_xor(acc.y, 32);
    acc.z += __shfl_xor(acc.z, 16); acc.z += __shfl_xor(acc.z, 32);
    acc.w += __shfl_xor(acc.w, 16); acc.w += __shfl_xor(acc.w, 32);
    den   += __shfl_xor(den, 16);   den   += __shfl_xor(den, 32);
    saw   += __shfl_xor(saw, 16);   saw   += __shfl_xor(saw, 32);

    float4 skv = *(const float4*)(sk + nb + g16 * 4);
    float inv = 1.f / (den + 1e-16f);
    float4 o;
    o.x = fmaf(saw, wev.x, acc.x) * inv + skv.x;
    o.y = fmaf(saw, wev.y, acc.y) * inv + skv.y;
    o.z = fmaf(saw, wev.z, acc.z) * inv + skv.z;
    o.w = fmaf(saw, wev.w, acc.w) * inv + skv.w;
    if (do_relu) {
        o.x = fmaxf(o.x, 0.f); o.y = fmaxf(o.y, 0.f);
        o.z = fmaxf(o.z, 0.f); o.w = fmaxf(o.w, 0.f);
    }
    if (lane < 16) *(float4*)(out + nb + g16 * 4) = o;

    if (do_pool) {
        int b = batch[node];
        if (lane < 16) {
            float* gp = gsum + (size_t)b * 64 + g16 * 4;
            atomicAdd(gp + 0, o.x);
            atomicAdd(gp + 1, o.y);
            atomicAdd(gp + 2, o.z);
            atomicAdd(gp + 3, o.w);
        }
        if (lane == 0) atomicAdd(&gcnt[b], 1.f);
    }
}

// ---------------------------------------------------------------------------
// mean-pool finalize + 3-layer MLP head; one block (128 thr) per graph
// ---------------------------------------------------------------------------
__global__ __launch_bounds__(128) void pool_mlp(
    const float* __restrict__ gsum, const float* __restrict__ gcnt,
    const float* __restrict__ W1, const float* __restrict__ b1,
    const float* __restrict__ W2, const float* __restrict__ b2,
    const float* __restrict__ W3, const float* __restrict__ b3,
    float* __restrict__ out)
{
    __shared__ float g[64];
    __shared__ float h1s[64];
    __shared__ float h2s[16];
    int b = blockIdx.x, t = threadIdx.x;

    if (t < 64) {
        float c = gcnt[b];
        g[t] = gsum[(size_t)b * 64 + t] / fmaxf(c, 1.f);
    }
    __syncthreads();
    if (t < 64) {
        float a = b1[t];
        #pragma unroll
        for (int i = 0; i < 64; ++i) a = fmaf(g[i], W1[i * 64 + t], a);
        h1s[t] = fmaxf(a, 0.f);
    }
    __syncthreads();
    if (t < 16) {
        float a = b2[t];
        #pragma unroll
        for (int i = 0; i < 64; ++i) a = fmaf(h1s[i], W2[i * 16 + t], a);
        h2s[t] = fmaxf(a, 0.f);
    }
    __syncthreads();
    float a = b3[t];
    #pragma unroll
    for (int i = 0; i < 16; ++i) a = fmaf(h2s[i], W3[i * 128 + t], a);
    out[(size_t)b * 128 + t] = a;
}

// ---------------------------------------------------------------------------
extern "C" void kernel_launch(void* const* d_in, const int* in_sizes, int n_in,
                              void* d_out, int out_size, void* d_ws, size_t ws_size,
                              hipStream_t stream) {
    const float* x         = (const float*)d_in[0];
    const float* edge_attr = (const float*)d_in[1];
    const int*   edge_index= (const int*)d_in[2];
    const int*   batch     = (const int*)d_in[3];
    const float* Wq   = (const float*)d_in[4];
    const float* bq   = (const float*)d_in[5];
    const float* Wk   = (const float*)d_in[6];
    const float* bk   = (const float*)d_in[7];
    const float* Wv   = (const float*)d_in[8];
    const float* bv   = (const float*)d_in[9];
    const float* We   = (const float*)d_in[10];
    const float* Wsk  = (const float*)d_in[11];
    const float* bsk  = (const float*)d_in[12];
    const float* W1   = (const float*)d_in[13];
    const float* b1   = (const float*)d_in[14];
    const float* W2   = (const float*)d_in[15];
    const float* b2   = (const float*)d_in[16];
    const float* W3   = (const float*)d_in[17];
    const float* b3   = (const float*)d_in[18];

    float* out        = (float*)d_out;
    float* node_emb   = out;                         // N*64
    float* graph_feat = out + (size_t)NN * 64;       // G*128

    float* wsf    = (float*)d_ws;
    float* q      = wsf;
    float* kvb    = q    + (size_t)NN * 64;          // N*128 packed k|v
    float* skp    = kvb  + (size_t)NN * 128;
    float* h      = skp  + (size_t)NN * 64;
    float* attr_s = h    + (size_t)NN * 64;
    int*   src_s  = (int*)(attr_s + EE);
    int*   row_ptr= src_s + EE;
    int*   wpos   = row_ptr + (NN + 1);
    float* gsum   = (float*)(wpos + NN);
    float* gcnt   = gsum + (size_t)GG * 64;

    // ---- CSR build (dst-sorted edges); reused by all 3 layers ----
    zero_i32<<<(NN + 255) / 256, 256, 0, stream>>>(wpos, NN);
    zero_f32<<<(GG * 64 + GG + 255) / 256, 256, 0, stream>>>(gsum, GG * 64 + GG);
    hist_kernel<<<(EE + 255) / 256, 256, 0, stream>>>(edge_index + EE, wpos);
    scan_kernel<<<1, 1024, 0, stream>>>(wpos, row_ptr, wpos);
    scatter_kernel<<<(EE + 255) / 256, 256, 0, stream>>>(edge_index, edge_attr,
                                                         wpos, src_s, attr_s);

    int gemm_grid = (NN + 31) / 32;
    int attn_grid = (NN + 3) / 4;

    const float* layer_in = x;
    for (int l = 0; l < LL; ++l) {
        const float* Wq_l = Wq + (size_t)l * 64 * 64;
        const float* Wk_l = Wk + (size_t)l * 64 * 64;
        const float* Wv_l = Wv + (size_t)l * 64 * 64;
        const float* Ws_l = Wsk + (size_t)l * 64 * 64;
        const float* bq_l = bq + (size_t)l * 64;
        const float* bk_l = bk + (size_t)l * 64;
        const float* bv_l = bv + (size_t)l * 64;
        const float* bs_l = bsk + (size_t)l * 64;
        const float* We_l = We + (size_t)l * 64;

        node_gemm<<<gemm_grid, 256, 0, stream>>>(layer_in,
            Wq_l, bq_l, Wk_l, bk_l, Wv_l, bv_l, Ws_l, bs_l,
            q, kvb, skp);

        int last = (l == LL - 1);
        float* dst_h = last ? node_emb : h;
        node_attn<<<attn_grid, 256, 0, stream>>>(q, kvb, skp, We_l,
            row_ptr, src_s, attr_s,
            dst_h, /*relu=*/!last, /*pool=*/last,
            batch, gsum, gcnt);

        layer_in = h;
    }

    pool_mlp<<<GG, 128, 0, stream>>>(gsum, gcnt, W1, b1, W2, b2, W3, b3, graph_feat);
}

// Round 2
// 593.528 us; speedup vs baseline: 1.0924x; 1.0924x over previous
//
#include <hip/hip_runtime.h>
#include <hip/hip_fp16.h>

#define NN 50000
#define EE 800000
#define LL 3
#define HH 4
#define CC 16
#define DD 64
#define GG 512
#define GRAPH_DIM 128

// ---------------------------------------------------------------------------
// utility: zero int / float ranges
// ---------------------------------------------------------------------------
__global__ void zero_i32(int* p, int n) {
    int i = blockIdx.x * blockDim.x + threadIdx.x;
    if (i < n) p[i] = 0;
}
__global__ void zero_f32(float* p, int n) {
    int i = blockIdx.x * blockDim.x + threadIdx.x;
    if (i < n) p[i] = 0.f;
}

// ---------------------------------------------------------------------------
// CSR build: histogram of dst, exclusive scan, scatter (src, attr) by dst
// ---------------------------------------------------------------------------
__global__ void hist_kernel(const int* __restrict__ dst, int* __restrict__ counts) {
    int e = blockIdx.x * blockDim.x + threadIdx.x;
    if (e < EE) atomicAdd(&counts[dst[e]], 1);
}

__global__ __launch_bounds__(1024) void scan_kernel(const int* __restrict__ counts,
                                                    int* __restrict__ row_ptr,
                                                    int* __restrict__ writepos) {
    __shared__ int wsum[16];
    int t = threadIdx.x, lane = t & 63, wid = t >> 6;
    int base = 0;
    for (int start = 0; start < NN; start += 1024) {
        int idx = start + t;
        int val = (idx < NN) ? counts[idx] : 0;
        int x = val;
        #pragma unroll
        for (int o = 1; o < 64; o <<= 1) {
            int y = __shfl_up(x, o);
            if (lane >= o) x += y;
        }
        if (lane == 63) wsum[wid] = x;
        __syncthreads();
        if (wid == 0) {
            int s = (lane < 16) ? wsum[lane] : 0;
            #pragma unroll
            for (int o = 1; o < 16; o <<= 1) {
                int y = __shfl_up(s, o);
                if (lane >= o) s += y;
            }
            if (lane < 16) wsum[lane] = s;
        }
        __syncthreads();
        int excl = x - val + base + (wid > 0 ? wsum[wid - 1] : 0);
        if (idx < NN) { row_ptr[idx] = excl; writepos[idx] = excl; }
        int total = wsum[15];
        __syncthreads();
        base += total;
    }
    if (t == 0) row_ptr[NN] = base;
}

__global__ void scatter_kernel(const int* __restrict__ ei, const float* __restrict__ attr,
                               int* __restrict__ writepos,
                               int* __restrict__ src_s, float* __restrict__ attr_s) {
    int e = blockIdx.x * blockDim.x + threadIdx.x;
    if (e < EE) {
        int s = ei[e];
        int d = ei[EE + e];
        int p = atomicAdd(&writepos[d], 1);
        src_s[p] = s;
        attr_s[p] = attr[e];
    }
}

// ---------------------------------------------------------------------------
// fused node GEMM: q = h@Wq+bq (f32) ; sk = h@Ws+bs (f32)
// kvh[node*64 + j] = half2( (h@Wk+bk)_j , (h@Wv+bv)_j )
//   -> one 4B dword per (node,channel) holds BOTH k and v, so node_attn
//      gathers k AND v with a single dword load per edge per lane.
//   k-wave and v-wave write disjoint 2B halves of each dword (byte-enable
//   granular stores, race-free).
// ---------------------------------------------------------------------------
__global__ __launch_bounds__(256) void node_gemm(
    const float* __restrict__ hx,
    const float* __restrict__ Wq, const float* __restrict__ bq,
    const float* __restrict__ Wk, const float* __restrict__ bk,
    const float* __restrict__ Wv, const float* __restrict__ bv,
    const float* __restrict__ Ws, const float* __restrict__ bs,
    float* __restrict__ q, __half* __restrict__ kvh, float* __restrict__ sk)
{
    __shared__ float xs[32 * 64];
    int t = threadIdx.x;
    int node0 = blockIdx.x * 32;

    const float4* src4 = (const float4*)(hx + (size_t)node0 * 64);
    float4* dst4 = (float4*)xs;
    #pragma unroll
    for (int r = 0; r < 2; ++r) {
        int i4 = t + r * 256;
        int node = node0 + (i4 >> 4);
        float4 val = make_float4(0.f, 0.f, 0.f, 0.f);
        if (node < NN) val = src4[i4];
        dst4[i4] = val;
    }
    __syncthreads();

    int mat = t >> 6, j = t & 63;
    const float* W = (mat == 0) ? Wq : (mat == 1) ? Wk : (mat == 2) ? Wv : Ws;
    const float* B = (mat == 0) ? bq : (mat == 1) ? bk : (mat == 2) ? bv : bs;

    float wcol[64];
    #pragma unroll
    for (int i = 0; i < 64; ++i) wcol[i] = W[i * 64 + j];
    float bj = B[j];

    for (int n = 0; n < 32; ++n) {
        int node = node0 + n;
        if (node >= NN) break;
        float acc = bj;
        const float4* xr = (const float4*)(xs + n * 64);
        #pragma unroll
        for (int i4 = 0; i4 < 16; ++i4) {
            float4 xv = xr[i4];
            acc = fmaf(xv.x, wcol[4 * i4 + 0], acc);
            acc = fmaf(xv.y, wcol[4 * i4 + 1], acc);
            acc = fmaf(xv.z, wcol[4 * i4 + 2], acc);
            acc = fmaf(xv.w, wcol[4 * i4 + 3], acc);
        }
        size_t idx = (size_t)node * 64 + j;
        if (mat == 0)      q[idx]  = acc;
        else if (mat == 3) sk[idx] = acc;
        else kvh[idx * 2 + (mat == 2)] = __float2half_rn(acc);
    }
}

// ---------------------------------------------------------------------------
// node-centric attention: one wave per dst node, lane = channel (R0 layout).
// k,v gathered together as one packed half2 dword per lane per edge:
//   half the cache lines (4/edge vs 8), one round-trip instead of two.
// 8-way edge unroll keeps 8 independent gathers in flight.
// Algebra hoisted:  score = (q.k + a*(q.we))/4 ; sum ex*(v+a*we)
//                   = sum(ex*v) + we*sum(ex*a)
// ---------------------------------------------------------------------------
__global__ __launch_bounds__(256) void node_attn(
    const float* __restrict__ q, const __half* __restrict__ kvh,
    const float* __restrict__ sk,
    const float* __restrict__ We,
    const int* __restrict__ row_ptr, const int* __restrict__ src_s,
    const float* __restrict__ attr_s,
    float* __restrict__ out, int do_relu, int do_pool,
    const int* __restrict__ batch,
    float* __restrict__ gsum, float* __restrict__ gcnt)
{
    int node = blockIdx.x * 4 + (threadIdx.x >> 6);
    int lane = threadIdx.x & 63;
    if (node >= NN) return;

    size_t nb = (size_t)node * 64;
    float qv = q[nb + lane];
    float skv = sk[nb + lane];
    float we = We[lane];

    // loop-invariant per-head dot  qw = sum_{c in head} q*we  (same in 16 lanes)
    float qw = qv * we;
    qw += __shfl_xor(qw, 1);
    qw += __shfl_xor(qw, 2);
    qw += __shfl_xor(qw, 4);
    qw += __shfl_xor(qw, 8);

    int p0 = row_ptr[node];
    int p1 = row_ptr[node + 1];

    const __half2* kvp = (const __half2*)kvh;   // kvp[src*64 + lane] = (k, v)

    float acc = 0.f, den = 0.f, saw = 0.f;
    int p = p0;
    for (; p + 8 <= p1; p += 8) {
        int s0 = src_s[p + 0], s1 = src_s[p + 1];
        int s2 = src_s[p + 2], s3 = src_s[p + 3];
        int s4 = src_s[p + 4], s5 = src_s[p + 5];
        int s6 = src_s[p + 6], s7 = src_s[p + 7];
        float a0 = attr_s[p + 0], a1 = attr_s[p + 1];
        float a2 = attr_s[p + 2], a3 = attr_s[p + 3];
        float a4 = attr_s[p + 4], a5 = attr_s[p + 5];
        float a6 = attr_s[p + 6], a7 = attr_s[p + 7];

        __half2 h0 = kvp[(size_t)s0 * 64 + lane];
        __half2 h1 = kvp[(size_t)s1 * 64 + lane];
        __half2 h2 = kvp[(size_t)s2 * 64 + lane];
        __half2 h3 = kvp[(size_t)s3 * 64 + lane];
        __half2 h4 = kvp[(size_t)s4 * 64 + lane];
        __half2 h5 = kvp[(size_t)s5 * 64 + lane];
        __half2 h6 = kvp[(size_t)s6 * 64 + lane];
        __half2 h7 = kvp[(size_t)s7 * 64 + lane];

        float2 f0 = __half22float2(h0);
        float2 f1 = __half22float2(h1);
        float2 f2 = __half22float2(h2);
        float2 f3 = __half22float2(h3);
        float2 f4 = __half22float2(h4);
        float2 f5 = __half22float2(h5);
        float2 f6 = __half22float2(h6);
        float2 f7 = __half22float2(h7);

        float r0 = qv * f0.x, r1 = qv * f1.x, r2 = qv * f2.x, r3 = qv * f3.x;
        float r4 = qv * f4.x, r5 = qv * f5.x, r6 = qv * f6.x, r7 = qv * f7.x;
        r0 += __shfl_xor(r0, 1); r1 += __shfl_xor(r1, 1);
        r2 += __shfl_xor(r2, 1); r3 += __shfl_xor(r3, 1);
        r4 += __shfl_xor(r4, 1); r5 += __shfl_xor(r5, 1);
        r6 += __shfl_xor(r6, 1); r7 += __shfl_xor(r7, 1);
        r0 += __shfl_xor(r0, 2); r1 += __shfl_xor(r1, 2);
        r2 += __shfl_xor(r2, 2); r3 += __shfl_xor(r3, 2);
        r4 += __shfl_xor(r4, 2); r5 += __shfl_xor(r5, 2);
        r6 += __shfl_xor(r6, 2); r7 += __shfl_xor(r7, 2);
        r0 += __shfl_xor(r0, 4); r1 += __shfl_xor(r1, 4);
        r2 += __shfl_xor(r2, 4); r3 += __shfl_xor(r3, 4);
        r4 += __shfl_xor(r4, 4); r5 += __shfl_xor(r5, 4);
        r6 += __shfl_xor(r6, 4); r7 += __shfl_xor(r7, 4);
        r0 += __shfl_xor(r0, 8); r1 += __shfl_xor(r1, 8);
        r2 += __shfl_xor(r2, 8); r3 += __shfl_xor(r3, 8);
        r4 += __shfl_xor(r4, 8); r5 += __shfl_xor(r5, 8);
        r6 += __shfl_xor(r6, 8); r7 += __shfl_xor(r7, 8);

        float e0 = __expf(fmaf(a0, qw, r0) * 0.25f);
        float e1 = __expf(fmaf(a1, qw, r1) * 0.25f);
        float e2 = __expf(fmaf(a2, qw, r2) * 0.25f);
        float e3 = __expf(fmaf(a3, qw, r3) * 0.25f);
        float e4 = __expf(fmaf(a4, qw, r4) * 0.25f);
        float e5 = __expf(fmaf(a5, qw, r5) * 0.25f);
        float e6 = __expf(fmaf(a6, qw, r6) * 0.25f);
        float e7 = __expf(fmaf(a7, qw, r7) * 0.25f);

        acc = fmaf(e0, f0.y, acc); den += e0; saw = fmaf(e0, a0, saw);
        acc = fmaf(e1, f1.y, acc); den += e1; saw = fmaf(e1, a1, saw);
        acc = fmaf(e2, f2.y, acc); den += e2; saw = fmaf(e2, a2, saw);
        acc = fmaf(e3, f3.y, acc); den += e3; saw = fmaf(e3, a3, saw);
        acc = fmaf(e4, f4.y, acc); den += e4; saw = fmaf(e4, a4, saw);
        acc = fmaf(e5, f5.y, acc); den += e5; saw = fmaf(e5, a5, saw);
        acc = fmaf(e6, f6.y, acc); den += e6; saw = fmaf(e6, a6, saw);
        acc = fmaf(e7, f7.y, acc); den += e7; saw = fmaf(e7, a7, saw);
    }
    for (; p < p1; ++p) {
        int s = src_s[p];
        float a = attr_s[p];
        __half2 hv = kvp[(size_t)s * 64 + lane];
        float2 f = __half22float2(hv);
        float r = qv * f.x;
        r += __shfl_xor(r, 1);
        r += __shfl_xor(r, 2);
        r += __shfl_xor(r, 4);
        r += __shfl_xor(r, 8);
        float ex = __expf(fmaf(a, qw, r) * 0.25f);
        acc = fmaf(ex, f.y, acc);
        den += ex;
        saw = fmaf(ex, a, saw);
    }

    float o = (acc + saw * we) / (den + 1e-16f) + skv;
    if (do_relu) o = fmaxf(o, 0.f);
    out[nb + lane] = o;

    if (do_pool) {
        int b = batch[node];
        atomicAdd(&gsum[(size_t)b * 64 + lane], o);
        if (lane == 0) atomicAdd(&gcnt[b], 1.f);
    }
}

// ---------------------------------------------------------------------------
// mean-pool finalize + 3-layer MLP head; one block (128 thr) per graph
// ---------------------------------------------------------------------------
__global__ __launch_bounds__(128) void pool_mlp(
    const float* __restrict__ gsum, const float* __restrict__ gcnt,
    const float* __restrict__ W1, const float* __restrict__ b1,
    const float* __restrict__ W2, const float* __restrict__ b2,
    const float* __restrict__ W3, const float* __restrict__ b3,
    float* __restrict__ out)
{
    __shared__ float g[64];
    __shared__ float h1s[64];
    __shared__ float h2s[16];
    int b = blockIdx.x, t = threadIdx.x;

    if (t < 64) {
        float c = gcnt[b];
        g[t] = gsum[(size_t)b * 64 + t] / fmaxf(c, 1.f);
    }
    __syncthreads();
    if (t < 64) {
        float a = b1[t];
        #pragma unroll
        for (int i = 0; i < 64; ++i) a = fmaf(g[i], W1[i * 64 + t], a);
        h1s[t] = fmaxf(a, 0.f);
    }
    __syncthreads();
    if (t < 16) {
        float a = b2[t];
        #pragma unroll
        for (int i = 0; i < 64; ++i) a = fmaf(h1s[i], W2[i * 16 + t], a);
        h2s[t] = fmaxf(a, 0.f);
    }
    __syncthreads();
    float a = b3[t];
    #pragma unroll
    for (int i = 0; i < 16; ++i) a = fmaf(h2s[i], W3[i * 128 + t], a);
    out[(size_t)b * 128 + t] = a;
}

// ---------------------------------------------------------------------------
extern "C" void kernel_launch(void* const* d_in, const int* in_sizes, int n_in,
                              void* d_out, int out_size, void* d_ws, size_t ws_size,
                              hipStream_t stream) {
    const float* x         = (const float*)d_in[0];
    const float* edge_attr = (const float*)d_in[1];
    const int*   edge_index= (const int*)d_in[2];
    const int*   batch     = (const int*)d_in[3];
    const float* Wq   = (const float*)d_in[4];
    const float* bq   = (const float*)d_in[5];
    const float* Wk   = (const float*)d_in[6];
    const float* bk   = (const float*)d_in[7];
    const float* Wv   = (const float*)d_in[8];
    const float* bv   = (const float*)d_in[9];
    const float* We   = (const float*)d_in[10];
    const float* Wsk  = (const float*)d_in[11];
    const float* bsk  = (const float*)d_in[12];
    const float* W1   = (const float*)d_in[13];
    const float* b1   = (const float*)d_in[14];
    const float* W2   = (const float*)d_in[15];
    const float* b2   = (const float*)d_in[16];
    const float* W3   = (const float*)d_in[17];
    const float* b3   = (const float*)d_in[18];

    float* out        = (float*)d_out;
    float* node_emb   = out;                         // N*64
    float* graph_feat = out + (size_t)NN * 64;       // G*128

    float* wsf    = (float*)d_ws;
    float* q      = wsf;
    float* kvf    = q    + (size_t)NN * 64;          // N*64 dwords: packed half2(k,v)
    float* skp    = kvf  + (size_t)NN * 64;
    float* h      = skp  + (size_t)NN * 64;
    float* attr_s = h    + (size_t)NN * 64;
    int*   src_s  = (int*)(attr_s + EE);
    int*   row_ptr= src_s + EE;
    int*   wpos   = row_ptr + (NN + 1);
    float* gsum   = (float*)(wpos + NN);
    float* gcnt   = gsum + (size_t)GG * 64;
    __half* kvh   = (__half*)kvf;

    // ---- CSR build (dst-sorted edges); reused by all 3 layers ----
    zero_i32<<<(NN + 255) / 256, 256, 0, stream>>>(wpos, NN);
    zero_f32<<<(GG * 64 + GG + 255) / 256, 256, 0, stream>>>(gsum, GG * 64 + GG);
    hist_kernel<<<(EE + 255) / 256, 256, 0, stream>>>(edge_index + EE, wpos);
    scan_kernel<<<1, 1024, 0, stream>>>(wpos, row_ptr, wpos);
    scatter_kernel<<<(EE + 255) / 256, 256, 0, stream>>>(edge_index, edge_attr,
                                                         wpos, src_s, attr_s);

    int gemm_grid = (NN + 31) / 32;
    int attn_grid = (NN + 3) / 4;

    const float* layer_in = x;
    for (int l = 0; l < LL; ++l) {
        const float* Wq_l = Wq + (size_t)l * 64 * 64;
        const float* Wk_l = Wk + (size_t)l * 64 * 64;
        const float* Wv_l = Wv + (size_t)l * 64 * 64;
        const float* Ws_l = Wsk + (size_t)l * 64 * 64;
        const float* bq_l = bq + (size_t)l * 64;
        const float* bk_l = bk + (size_t)l * 64;
        const float* bv_l = bv + (size_t)l * 64;
        const float* bs_l = bsk + (size_t)l * 64;
        const float* We_l = We + (size_t)l * 64;

        node_gemm<<<gemm_grid, 256, 0, stream>>>(layer_in,
            Wq_l, bq_l, Wk_l, bk_l, Wv_l, bv_l, Ws_l, bs_l,
            q, kvh, skp);

        int last = (l == LL - 1);
        float* dst_h = last ? node_emb : h;
        node_attn<<<attn_grid, 256, 0, stream>>>(q, kvh, skp, We_l,
            row_ptr, src_s, attr_s,
            dst_h, /*relu=*/!last, /*pool=*/last,
            batch, gsum, gcnt);

        layer_in = h;
    }

    pool_mlp<<<GG, 128, 0, stream>>>(gsum, gcnt, W1, b1, W2, b2, W3, b3, graph_feat);
}

// Round 3
// 584.053 us; speedup vs baseline: 1.1101x; 1.0162x over previous
//
#include <hip/hip_runtime.h>
#include <hip/hip_fp16.h>

#define NN 50000
#define EE 800000
#define LL 3
#define HH 4
#define CC 16
#define DD 64
#define GG 512
#define GRAPH_DIM 128

// ---------------------------------------------------------------------------
// utility: zero int / float ranges
// ---------------------------------------------------------------------------
__global__ void zero_i32(int* p, int n) {
    int i = blockIdx.x * blockDim.x + threadIdx.x;
    if (i < n) p[i] = 0;
}
__global__ void zero_f32(float* p, int n) {
    int i = blockIdx.x * blockDim.x + threadIdx.x;
    if (i < n) p[i] = 0.f;
}

// ---------------------------------------------------------------------------
// CSR build: histogram of dst, exclusive scan, scatter (src, attr) by dst
// ---------------------------------------------------------------------------
__global__ void hist_kernel(const int* __restrict__ dst, int* __restrict__ counts) {
    int e = blockIdx.x * blockDim.x + threadIdx.x;
    if (e < EE) atomicAdd(&counts[dst[e]], 1);
}

__global__ __launch_bounds__(1024) void scan_kernel(const int* __restrict__ counts,
                                                    int* __restrict__ row_ptr,
                                                    int* __restrict__ writepos) {
    __shared__ int wsum[16];
    int t = threadIdx.x, lane = t & 63, wid = t >> 6;
    int base = 0;
    for (int start = 0; start < NN; start += 1024) {
        int idx = start + t;
        int val = (idx < NN) ? counts[idx] : 0;
        int x = val;
        #pragma unroll
        for (int o = 1; o < 64; o <<= 1) {
            int y = __shfl_up(x, o);
            if (lane >= o) x += y;
        }
        if (lane == 63) wsum[wid] = x;
        __syncthreads();
        if (wid == 0) {
            int s = (lane < 16) ? wsum[lane] : 0;
            #pragma unroll
            for (int o = 1; o < 16; o <<= 1) {
                int y = __shfl_up(s, o);
                if (lane >= o) s += y;
            }
            if (lane < 16) wsum[lane] = s;
        }
        __syncthreads();
        int excl = x - val + base + (wid > 0 ? wsum[wid - 1] : 0);
        if (idx < NN) { row_ptr[idx] = excl; writepos[idx] = excl; }
        int total = wsum[15];
        __syncthreads();
        base += total;
    }
    if (t == 0) row_ptr[NN] = base;
}

__global__ void scatter_kernel(const int* __restrict__ ei, const float* __restrict__ attr,
                               int* __restrict__ writepos,
                               int* __restrict__ src_s, float* __restrict__ attr_s) {
    int e = blockIdx.x * blockDim.x + threadIdx.x;
    if (e < EE) {
        int s = ei[e];
        int d = ei[EE + e];
        int p = atomicAdd(&writepos[d], 1);
        src_s[p] = s;
        attr_s[p] = attr[e];
    }
}

// ---------------------------------------------------------------------------
// fused node GEMM: q = h@Wq+bq (f32) ; sk = h@Ws+bs (f32)
// kvh[node*64 + j] = half2( (h@Wk+bk)_j , (h@Wv+bv)_j )
// ---------------------------------------------------------------------------
__global__ __launch_bounds__(256) void node_gemm(
    const float* __restrict__ hx,
    const float* __restrict__ Wq, const float* __restrict__ bq,
    const float* __restrict__ Wk, const float* __restrict__ bk,
    const float* __restrict__ Wv, const float* __restrict__ bv,
    const float* __restrict__ Ws, const float* __restrict__ bs,
    float* __restrict__ q, __half* __restrict__ kvh, float* __restrict__ sk)
{
    __shared__ float xs[32 * 64];
    int t = threadIdx.x;
    int node0 = blockIdx.x * 32;

    const float4* src4 = (const float4*)(hx + (size_t)node0 * 64);
    float4* dst4 = (float4*)xs;
    #pragma unroll
    for (int r = 0; r < 2; ++r) {
        int i4 = t + r * 256;
        int node = node0 + (i4 >> 4);
        float4 val = make_float4(0.f, 0.f, 0.f, 0.f);
        if (node < NN) val = src4[i4];
        dst4[i4] = val;
    }
    __syncthreads();

    int mat = t >> 6, j = t & 63;
    const float* W = (mat == 0) ? Wq : (mat == 1) ? Wk : (mat == 2) ? Wv : Ws;
    const float* B = (mat == 0) ? bq : (mat == 1) ? bk : (mat == 2) ? bv : bs;

    float wcol[64];
    #pragma unroll
    for (int i = 0; i < 64; ++i) wcol[i] = W[i * 64 + j];
    float bj = B[j];

    for (int n = 0; n < 32; ++n) {
        int node = node0 + n;
        if (node >= NN) break;
        float acc = bj;
        const float4* xr = (const float4*)(xs + n * 64);
        #pragma unroll
        for (int i4 = 0; i4 < 16; ++i4) {
            float4 xv = xr[i4];
            acc = fmaf(xv.x, wcol[4 * i4 + 0], acc);
            acc = fmaf(xv.y, wcol[4 * i4 + 1], acc);
            acc = fmaf(xv.z, wcol[4 * i4 + 2], acc);
            acc = fmaf(xv.w, wcol[4 * i4 + 3], acc);
        }
        size_t idx = (size_t)node * 64 + j;
        if (mat == 0)      q[idx]  = acc;
        else if (mat == 3) sk[idx] = acc;
        else kvh[idx * 2 + (mat == 2)] = __float2half_rn(acc);
    }
}

// ---------------------------------------------------------------------------
// node-centric attention, TRANSPOSED lane layout:
//   lane = head*16 + edge_slot.  Each lane owns ALL 16 channels of one head
//   for one edge (in registers).  Score = in-lane 16-ch dot (NO per-edge
//   cross-lane shuffles).  V partials accumulate in-lane into acc[16];
//   one LDS transpose per NODE converts to channel layout at the end.
//   Whole 16-edge row gathered at once: 4x dwordx4 per lane = 16 edges x
//   256B in flight, one vmem wait per row.
//   den/saw: 4x shfl_xor once per node; lane==channel identity makes the
//   head-broadcast free (lane c is already in head c/16's lane group).
// ---------------------------------------------------------------------------
static __device__ __forceinline__ float2 h2f2(unsigned u) {
    __half2 h = __builtin_bit_cast(__half2, u);
    return __half22float2(h);
}

__global__ __launch_bounds__(256) void node_attn(
    const float* __restrict__ q, const __half* __restrict__ kvh,
    const float* __restrict__ sk, const float* __restrict__ We,
    const int* __restrict__ row_ptr, const int* __restrict__ src_s,
    const float* __restrict__ attr_s,
    float* __restrict__ out, int do_relu, int do_pool,
    const int* __restrict__ batch,
    float* __restrict__ gsum, float* __restrict__ gcnt)
{
    __shared__ float lds[4 * 16 * 68];   // per-wave [edge][68] transpose buffer
    int wid  = threadIdx.x >> 6;
    int lane = threadIdx.x & 63;
    int node = blockIdx.x * 4 + wid;
    if (node >= NN) return;

    int eslot = lane & 15;   // edge slot within 16-edge row chunk
    int head  = lane >> 4;   // head 0..3 (owns channels 16h..16h+15)

    // q slice (fp32) and We slice for my head — registers
    const float4* q4 = (const float4*)(q + (size_t)node * 64 + head * 16);
    float4 q0 = q4[0], q1 = q4[1], q2 = q4[2], q3 = q4[3];
    const float4* w4 = (const float4*)(We + head * 16);
    float4 w0 = w4[0], w1 = w4[1], w2 = w4[2], w3 = w4[3];

    // qw = q . We over my head's 16 channels (in-lane)
    float qw = q0.x * w0.x;
    qw = fmaf(q0.y, w0.y, qw); qw = fmaf(q0.z, w0.z, qw); qw = fmaf(q0.w, w0.w, qw);
    qw = fmaf(q1.x, w1.x, qw); qw = fmaf(q1.y, w1.y, qw); qw = fmaf(q1.z, w1.z, qw); qw = fmaf(q1.w, w1.w, qw);
    qw = fmaf(q2.x, w2.x, qw); qw = fmaf(q2.y, w2.y, qw); qw = fmaf(q2.z, w2.z, qw); qw = fmaf(q2.w, w2.w, qw);
    qw = fmaf(q3.x, w3.x, qw); qw = fmaf(q3.y, w3.y, qw); qw = fmaf(q3.z, w3.z, qw); qw = fmaf(q3.w, w3.w, qw);

    int p0 = row_ptr[node];
    int p1 = row_ptr[node + 1];

    float accv[16];
    #pragma unroll
    for (int j = 0; j < 16; ++j) accv[j] = 0.f;
    float den = 0.f, saw = 0.f;

    const __half* kvbase = kvh + head * 32;   // + s*128 halfs per edge

    #pragma unroll 1
    for (int p = p0; p < p1; p += 16) {
        int e = p + eslot;
        int i = min(e, p1 - 1);
        int s = src_s[i];
        float a = attr_s[i];

        const uint4* kv4 = (const uint4*)(kvbase + (size_t)s * 128);
        uint4 u0 = kv4[0], u1 = kv4[1], u2 = kv4[2], u3 = kv4[3];

        float vt[16];
        float sc = 0.f;
        {
            float2 f;
            f = h2f2(u0.x); sc = fmaf(q0.x, f.x, sc); vt[0]  = f.y;
            f = h2f2(u0.y); sc = fmaf(q0.y, f.x, sc); vt[1]  = f.y;
            f = h2f2(u0.z); sc = fmaf(q0.z, f.x, sc); vt[2]  = f.y;
            f = h2f2(u0.w); sc = fmaf(q0.w, f.x, sc); vt[3]  = f.y;
            f = h2f2(u1.x); sc = fmaf(q1.x, f.x, sc); vt[4]  = f.y;
            f = h2f2(u1.y); sc = fmaf(q1.y, f.x, sc); vt[5]  = f.y;
            f = h2f2(u1.z); sc = fmaf(q1.z, f.x, sc); vt[6]  = f.y;
            f = h2f2(u1.w); sc = fmaf(q1.w, f.x, sc); vt[7]  = f.y;
            f = h2f2(u2.x); sc = fmaf(q2.x, f.x, sc); vt[8]  = f.y;
            f = h2f2(u2.y); sc = fmaf(q2.y, f.x, sc); vt[9]  = f.y;
            f = h2f2(u2.z); sc = fmaf(q2.z, f.x, sc); vt[10] = f.y;
            f = h2f2(u2.w); sc = fmaf(q2.w, f.x, sc); vt[11] = f.y;
            f = h2f2(u3.x); sc = fmaf(q3.x, f.x, sc); vt[12] = f.y;
            f = h2f2(u3.y); sc = fmaf(q3.y, f.x, sc); vt[13] = f.y;
            f = h2f2(u3.z); sc = fmaf(q3.z, f.x, sc); vt[14] = f.y;
            f = h2f2(u3.w); sc = fmaf(q3.w, f.x, sc); vt[15] = f.y;
        }

        float w = __expf(fmaf(a, qw, sc) * 0.25f);
        if (e >= p1) w = 0.f;           // mask tail lanes

        den += w;
        saw = fmaf(w, a, saw);
        #pragma unroll
        for (int j = 0; j < 16; ++j) accv[j] = fmaf(w, vt[j], accv[j]);
    }

    // den/saw: reduce across the 16 edge-lanes of this head (stays in group)
    den += __shfl_xor(den, 1); den += __shfl_xor(den, 2);
    den += __shfl_xor(den, 4); den += __shfl_xor(den, 8);
    saw += __shfl_xor(saw, 1); saw += __shfl_xor(saw, 2);
    saw += __shfl_xor(saw, 4); saw += __shfl_xor(saw, 8);

    // acc transpose: (head,edge) partials -> per-channel totals via LDS.
    // row stride 68 floats => write banks spread (2-way max), reads conflict-free.
    float* buf = lds + wid * (16 * 68);
    float4* bw = (float4*)(buf + eslot * 68 + head * 16);
    bw[0] = make_float4(accv[0],  accv[1],  accv[2],  accv[3]);
    bw[1] = make_float4(accv[4],  accv[5],  accv[6],  accv[7]);
    bw[2] = make_float4(accv[8],  accv[9],  accv[10], accv[11]);
    bw[3] = make_float4(accv[12], accv[13], accv[14], accv[15]);
    // same-wave LDS write->read: ordered via lgkmcnt (compiler-inserted)
    float tot = 0.f;
    #pragma unroll
    for (int e2 = 0; e2 < 16; ++e2) tot += buf[e2 * 68 + lane];

    // lane is now channel c; den/saw already hold head c/16's totals
    float wec = We[lane];
    float skv = sk[(size_t)node * 64 + lane];
    float o = fmaf(saw, wec, tot) / (den + 1e-16f) + skv;
    if (do_relu) o = fmaxf(o, 0.f);
    out[(size_t)node * 64 + lane] = o;

    if (do_pool) {
        int b = batch[node];
        atomicAdd(&gsum[(size_t)b * 64 + lane], o);
        if (lane == 0) atomicAdd(&gcnt[b], 1.f);
    }
}

// ---------------------------------------------------------------------------
// mean-pool finalize + 3-layer MLP head; one block (128 thr) per graph
// ---------------------------------------------------------------------------
__global__ __launch_bounds__(128) void pool_mlp(
    const float* __restrict__ gsum, const float* __restrict__ gcnt,
    const float* __restrict__ W1, const float* __restrict__ b1,
    const float* __restrict__ W2, const float* __restrict__ b2,
    const float* __restrict__ W3, const float* __restrict__ b3,
    float* __restrict__ out)
{
    __shared__ float g[64];
    __shared__ float h1s[64];
    __shared__ float h2s[16];
    int b = blockIdx.x, t = threadIdx.x;

    if (t < 64) {
        float c = gcnt[b];
        g[t] = gsum[(size_t)b * 64 + t] / fmaxf(c, 1.f);
    }
    __syncthreads();
    if (t < 64) {
        float a = b1[t];
        #pragma unroll
        for (int i = 0; i < 64; ++i) a = fmaf(g[i], W1[i * 64 + t], a);
        h1s[t] = fmaxf(a, 0.f);
    }
    __syncthreads();
    if (t < 16) {
        float a = b2[t];
        #pragma unroll
        for (int i = 0; i < 64; ++i) a = fmaf(h1s[i], W2[i * 16 + t], a);
        h2s[t] = fmaxf(a, 0.f);
    }
    __syncthreads();
    float a = b3[t];
    #pragma unroll
    for (int i = 0; i < 16; ++i) a = fmaf(h2s[i], W3[i * 128 + t], a);
    out[(size_t)b * 128 + t] = a;
}

// ---------------------------------------------------------------------------
extern "C" void kernel_launch(void* const* d_in, const int* in_sizes, int n_in,
                              void* d_out, int out_size, void* d_ws, size_t ws_size,
                              hipStream_t stream) {
    const float* x         = (const float*)d_in[0];
    const float* edge_attr = (const float*)d_in[1];
    const int*   edge_index= (const int*)d_in[2];
    const int*   batch     = (const int*)d_in[3];
    const float* Wq   = (const float*)d_in[4];
    const float* bq   = (const float*)d_in[5];
    const float* Wk   = (const float*)d_in[6];
    const float* bk   = (const float*)d_in[7];
    const float* Wv   = (const float*)d_in[8];
    const float* bv   = (const float*)d_in[9];
    const float* We   = (const float*)d_in[10];
    const float* Wsk  = (const float*)d_in[11];
    const float* bsk  = (const float*)d_in[12];
    const float* W1   = (const float*)d_in[13];
    const float* b1   = (const float*)d_in[14];
    const float* W2   = (const float*)d_in[15];
    const float* b2   = (const float*)d_in[16];
    const float* W3   = (const float*)d_in[17];
    const float* b3   = (const float*)d_in[18];

    float* out        = (float*)d_out;
    float* node_emb   = out;                         // N*64
    float* graph_feat = out + (size_t)NN * 64;       // G*128

    float* wsf    = (float*)d_ws;
    float* q      = wsf;
    float* kvf    = q    + (size_t)NN * 64;          // N*64 dwords: packed half2(k,v)
    float* skp    = kvf  + (size_t)NN * 64;
    float* h      = skp  + (size_t)NN * 64;
    float* attr_s = h    + (size_t)NN * 64;
    int*   src_s  = (int*)(attr_s + EE);
    int*   row_ptr= src_s + EE;
    int*   wpos   = row_ptr + (NN + 1);
    float* gsum   = (float*)(wpos + NN);
    float* gcnt   = gsum + (size_t)GG * 64;
    __half* kvh   = (__half*)kvf;

    // ---- CSR build (dst-sorted edges); reused by all 3 layers ----
    zero_i32<<<(NN + 255) / 256, 256, 0, stream>>>(wpos, NN);
    zero_f32<<<(GG * 64 + GG + 255) / 256, 256, 0, stream>>>(gsum, GG * 64 + GG);
    hist_kernel<<<(EE + 255) / 256, 256, 0, stream>>>(edge_index + EE, wpos);
    scan_kernel<<<1, 1024, 0, stream>>>(wpos, row_ptr, wpos);
    scatter_kernel<<<(EE + 255) / 256, 256, 0, stream>>>(edge_index, edge_attr,
                                                         wpos, src_s, attr_s);

    int gemm_grid = (NN + 31) / 32;
    int attn_grid = (NN + 3) / 4;

    const float* layer_in = x;
    for (int l = 0; l < LL; ++l) {
        const float* Wq_l = Wq + (size_t)l * 64 * 64;
        const float* Wk_l = Wk + (size_t)l * 64 * 64;
        const float* Wv_l = Wv + (size_t)l * 64 * 64;
        const float* Ws_l = Wsk + (size_t)l * 64 * 64;
        const float* bq_l = bq + (size_t)l * 64;
        const float* bk_l = bk + (size_t)l * 64;
        const float* bv_l = bv + (size_t)l * 64;
        const float* bs_l = bsk + (size_t)l * 64;
        const float* We_l = We + (size_t)l * 64;

        node_gemm<<<gemm_grid, 256, 0, stream>>>(layer_in,
            Wq_l, bq_l, Wk_l, bk_l, Wv_l, bv_l, Ws_l, bs_l,
            q, kvh, skp);

        int last = (l == LL - 1);
        float* dst_h = last ? node_emb : h;
        node_attn<<<attn_grid, 256, 0, stream>>>(q, kvh, skp, We_l,
            row_ptr, src_s, attr_s,
            dst_h, /*relu=*/!last, /*pool=*/last,
            batch, gsum, gcnt);

        layer_in = h;
    }

    pool_mlp<<<GG, 128, 0, stream>>>(gsum, gcnt, W1, b1, W2, b2, W3, b3, graph_feat);
}

// Round 4
// 539.189 us; speedup vs baseline: 1.2025x; 1.0832x over previous
//
#include <hip/hip_runtime.h>
#include <hip/hip_fp16.h>

#define NN 50000
#define EE 800000
#define LL 3
#define HH 4
#define CC 16
#define DD 64
#define GG 512
#define GRAPH_DIM 128

// ---------------------------------------------------------------------------
// utility: zero int / float ranges
// ---------------------------------------------------------------------------
__global__ void zero_i32(int* p, int n) {
    int i = blockIdx.x * blockDim.x + threadIdx.x;
    if (i < n) p[i] = 0;
}
__global__ void zero_f32(float* p, int n) {
    int i = blockIdx.x * blockDim.x + threadIdx.x;
    if (i < n) p[i] = 0.f;
}

// ---------------------------------------------------------------------------
// CSR build: histogram of dst, exclusive scan, scatter (src, attr) by dst
// ---------------------------------------------------------------------------
__global__ void hist_kernel(const int* __restrict__ dst, int* __restrict__ counts) {
    int e = blockIdx.x * blockDim.x + threadIdx.x;
    if (e < EE) atomicAdd(&counts[dst[e]], 1);
}

__global__ __launch_bounds__(1024) void scan_kernel(const int* __restrict__ counts,
                                                    int* __restrict__ row_ptr,
                                                    int* __restrict__ writepos) {
    __shared__ int wsum[16];
    int t = threadIdx.x, lane = t & 63, wid = t >> 6;
    int base = 0;
    for (int start = 0; start < NN; start += 1024) {
        int idx = start + t;
        int val = (idx < NN) ? counts[idx] : 0;
        int x = val;
        #pragma unroll
        for (int o = 1; o < 64; o <<= 1) {
            int y = __shfl_up(x, o);
            if (lane >= o) x += y;
        }
        if (lane == 63) wsum[wid] = x;
        __syncthreads();
        if (wid == 0) {
            int s = (lane < 16) ? wsum[lane] : 0;
            #pragma unroll
            for (int o = 1; o < 16; o <<= 1) {
                int y = __shfl_up(s, o);
                if (lane >= o) s += y;
            }
            if (lane < 16) wsum[lane] = s;
        }
        __syncthreads();
        int excl = x - val + base + (wid > 0 ? wsum[wid - 1] : 0);
        if (idx < NN) { row_ptr[idx] = excl; writepos[idx] = excl; }
        int total = wsum[15];
        __syncthreads();
        base += total;
    }
    if (t == 0) row_ptr[NN] = base;
}

__global__ void scatter_kernel(const int* __restrict__ ei, const float* __restrict__ attr,
                               int* __restrict__ writepos,
                               int* __restrict__ src_s, float* __restrict__ attr_s) {
    int e = blockIdx.x * blockDim.x + threadIdx.x;
    if (e < EE) {
        int s = ei[e];
        int d = ei[EE + e];
        int p = atomicAdd(&writepos[d], 1);
        src_s[p] = s;
        attr_s[p] = attr[e];
    }
}

// ---------------------------------------------------------------------------
// fused node GEMM: q = h@Wq+bq (f32) ; sk = h@Ws+bs (f32)
// kvh[node*64 + j] = half2( (h@Wk+bk)_j , (h@Wv+bv)_j )
// ---------------------------------------------------------------------------
__global__ __launch_bounds__(256) void node_gemm(
    const float* __restrict__ hx,
    const float* __restrict__ Wq, const float* __restrict__ bq,
    const float* __restrict__ Wk, const float* __restrict__ bk,
    const float* __restrict__ Wv, const float* __restrict__ bv,
    const float* __restrict__ Ws, const float* __restrict__ bs,
    float* __restrict__ q, __half* __restrict__ kvh, float* __restrict__ sk)
{
    __shared__ float xs[32 * 64];
    int t = threadIdx.x;
    int node0 = blockIdx.x * 32;

    const float4* src4 = (const float4*)(hx + (size_t)node0 * 64);
    float4* dst4 = (float4*)xs;
    #pragma unroll
    for (int r = 0; r < 2; ++r) {
        int i4 = t + r * 256;
        int node = node0 + (i4 >> 4);
        float4 val = make_float4(0.f, 0.f, 0.f, 0.f);
        if (node < NN) val = src4[i4];
        dst4[i4] = val;
    }
    __syncthreads();

    int mat = t >> 6, j = t & 63;
    const float* W = (mat == 0) ? Wq : (mat == 1) ? Wk : (mat == 2) ? Wv : Ws;
    const float* B = (mat == 0) ? bq : (mat == 1) ? bk : (mat == 2) ? bv : bs;

    float wcol[64];
    #pragma unroll
    for (int i = 0; i < 64; ++i) wcol[i] = W[i * 64 + j];
    float bj = B[j];

    for (int n = 0; n < 32; ++n) {
        int node = node0 + n;
        if (node >= NN) break;
        float acc = bj;
        const float4* xr = (const float4*)(xs + n * 64);
        #pragma unroll
        for (int i4 = 0; i4 < 16; ++i4) {
            float4 xv = xr[i4];
            acc = fmaf(xv.x, wcol[4 * i4 + 0], acc);
            acc = fmaf(xv.y, wcol[4 * i4 + 1], acc);
            acc = fmaf(xv.z, wcol[4 * i4 + 2], acc);
            acc = fmaf(xv.w, wcol[4 * i4 + 3], acc);
        }
        size_t idx = (size_t)node * 64 + j;
        if (mat == 0)      q[idx]  = acc;
        else if (mat == 3) sk[idx] = acc;
        else kvh[idx * 2 + (mat == 2)] = __float2half_rn(acc);
    }
}

// ---------------------------------------------------------------------------
// persistent node-centric attention (R3 lane layout, cross-node pipelined):
//   lane = head*16 + edge_slot;  each wave grid-strides over nodes.
//   Pipeline: row_ptr prefetched 2 nodes ahead; src/attr/q/sk prefetched
//   1 node ahead (a full iteration of latency cover); 8 kv dwordx4 gathers
//   (2 x 16-edge chunks) in flight per node.  Waves never die -> no
//   launch/drain gaps; ~15 independent vmem ops outstanding per wave.
// ---------------------------------------------------------------------------
static __device__ __forceinline__ float2 h2f2(unsigned u) {
    __half2 h = __builtin_bit_cast(__half2, u);
    return __half22float2(h);
}

// clamp edge index e into [p0, p1-1] and [0, EE-1] (mask handles validity)
static __device__ __forceinline__ int cidx(int e, int p0, int p1) {
    int hi = max(p1 - 1, p0);
    int i = min(e, hi);
    return min(i, EE - 1);
}

static __device__ __forceinline__ void chunk16(
    uint4 u0, uint4 u1, uint4 u2, uint4 u3,
    float4 q0, float4 q1, float4 q2, float4 q3,
    float a, float qw, int e, int p1,
    float* accv, float& den, float& saw)
{
    float vt[16];
    float sc = 0.f;
    float2 f;
    f = h2f2(u0.x); sc = fmaf(q0.x, f.x, sc); vt[0]  = f.y;
    f = h2f2(u0.y); sc = fmaf(q0.y, f.x, sc); vt[1]  = f.y;
    f = h2f2(u0.z); sc = fmaf(q0.z, f.x, sc); vt[2]  = f.y;
    f = h2f2(u0.w); sc = fmaf(q0.w, f.x, sc); vt[3]  = f.y;
    f = h2f2(u1.x); sc = fmaf(q1.x, f.x, sc); vt[4]  = f.y;
    f = h2f2(u1.y); sc = fmaf(q1.y, f.x, sc); vt[5]  = f.y;
    f = h2f2(u1.z); sc = fmaf(q1.z, f.x, sc); vt[6]  = f.y;
    f = h2f2(u1.w); sc = fmaf(q1.w, f.x, sc); vt[7]  = f.y;
    f = h2f2(u2.x); sc = fmaf(q2.x, f.x, sc); vt[8]  = f.y;
    f = h2f2(u2.y); sc = fmaf(q2.y, f.x, sc); vt[9]  = f.y;
    f = h2f2(u2.z); sc = fmaf(q2.z, f.x, sc); vt[10] = f.y;
    f = h2f2(u2.w); sc = fmaf(q2.w, f.x, sc); vt[11] = f.y;
    f = h2f2(u3.x); sc = fmaf(q3.x, f.x, sc); vt[12] = f.y;
    f = h2f2(u3.y); sc = fmaf(q3.y, f.x, sc); vt[13] = f.y;
    f = h2f2(u3.z); sc = fmaf(q3.z, f.x, sc); vt[14] = f.y;
    f = h2f2(u3.w); sc = fmaf(q3.w, f.x, sc); vt[15] = f.y;

    float w = __expf(fmaf(a, qw, sc) * 0.25f);
    if (e >= p1) w = 0.f;
    den += w;
    saw = fmaf(w, a, saw);
    #pragma unroll
    for (int j = 0; j < 16; ++j) accv[j] = fmaf(w, vt[j], accv[j]);
}

#define ATTN_BLOCKS 2048

__global__ __launch_bounds__(256) void node_attn(
    const float* __restrict__ q, const __half* __restrict__ kvh,
    const float* __restrict__ sk, const float* __restrict__ We,
    const int* __restrict__ row_ptr, const int* __restrict__ src_s,
    const float* __restrict__ attr_s,
    float* __restrict__ out, int do_relu, int do_pool,
    const int* __restrict__ batch,
    float* __restrict__ gsum, float* __restrict__ gcnt)
{
    __shared__ float lds[4 * 16 * 68];
    int wid   = threadIdx.x >> 6;
    int lane  = threadIdx.x & 63;
    int eslot = lane & 15;
    int head  = lane >> 4;

    const int NW = ATTN_BLOCKS * 4;
    int node = blockIdx.x * 4 + wid;
    if (node >= NN) return;

    float* buf = lds + wid * (16 * 68);

    // hoisted invariants
    const float4* w4 = (const float4*)(We + head * 16);
    float4 w0 = w4[0], w1 = w4[1], w2 = w4[2], w3 = w4[3];
    float wec = We[lane];
    const __half* kvbase = kvh + head * 32;

    // ---- prologue: fill pipeline for first node ----
    int p0c = row_ptr[node], p1c = row_ptr[node + 1];
    int i0 = cidx(p0c + eslot, p0c, p1c);
    int i1 = cidx(p0c + 16 + eslot, p0c, p1c);
    int   s0c = src_s[i0]; float a0c = attr_s[i0];
    int   s1c = src_s[i1]; float a1c = attr_s[i1];

    int nn1 = node + NW;
    int nn1c = (nn1 < NN) ? nn1 : node;
    int p0n = row_ptr[nn1c], p1n = row_ptr[nn1c + 1];

    const float4* qp = (const float4*)(q + (size_t)node * 64 + head * 16);
    float4 qc0 = qp[0], qc1 = qp[1], qc2 = qp[2], qc3 = qp[3];
    float skc = sk[(size_t)node * 64 + lane];

    for (;;) {
        // ---- prefetches for future nodes (covered by this iteration) ----
        int nx1 = node + NW;                  // next node
        int nx2 = node + 2 * NW;              // next-next node
        int nx1c = (nx1 < NN) ? nx1 : node;
        int nx2c = (nx2 < NN) ? nx2 : node;

        int p0n2 = row_ptr[nx2c];             // stage-2 row_ptr
        int p1n2 = row_ptr[nx2c + 1];

        int j0 = cidx(p0n + eslot, p0n, p1n); // stage-1 src/attr (rp arrived)
        int j1 = cidx(p0n + 16 + eslot, p0n, p1n);
        int   s0n = src_s[j0]; float a0n = attr_s[j0];
        int   s1n = src_s[j1]; float a1n = attr_s[j1];

        const float4* qpn = (const float4*)(q + (size_t)nx1c * 64 + head * 16);
        float4 qn0 = qpn[0], qn1 = qpn[1], qn2 = qpn[2], qn3 = qpn[3];
        float skn = sk[(size_t)nx1c * 64 + lane];

        // ---- current node: issue 8 kv gathers back-to-back ----
        const uint4* kva = (const uint4*)(kvbase + (size_t)s0c * 128);
        uint4 u0 = kva[0], u1 = kva[1], u2 = kva[2], u3 = kva[3];
        const uint4* kvb = (const uint4*)(kvbase + (size_t)s1c * 128);
        uint4 x0 = kvb[0], x1 = kvb[1], x2 = kvb[2], x3 = kvb[3];

        // qw = q . We for my head (in-lane, covers part of kv latency)
        float qw = qc0.x * w0.x;
        qw = fmaf(qc0.y, w0.y, qw); qw = fmaf(qc0.z, w0.z, qw); qw = fmaf(qc0.w, w0.w, qw);
        qw = fmaf(qc1.x, w1.x, qw); qw = fmaf(qc1.y, w1.y, qw); qw = fmaf(qc1.z, w1.z, qw); qw = fmaf(qc1.w, w1.w, qw);
        qw = fmaf(qc2.x, w2.x, qw); qw = fmaf(qc2.y, w2.y, qw); qw = fmaf(qc2.z, w2.z, qw); qw = fmaf(qc2.w, w2.w, qw);
        qw = fmaf(qc3.x, w3.x, qw); qw = fmaf(qc3.y, w3.y, qw); qw = fmaf(qc3.z, w3.z, qw); qw = fmaf(qc3.w, w3.w, qw);

        float accv[16];
        #pragma unroll
        for (int j = 0; j < 16; ++j) accv[j] = 0.f;
        float den = 0.f, saw = 0.f;

        chunk16(u0, u1, u2, u3, qc0, qc1, qc2, qc3,
                a0c, qw, p0c + eslot, p1c, accv, den, saw);
        chunk16(x0, x1, x2, x3, qc0, qc1, qc2, qc3,
                a1c, qw, p0c + 16 + eslot, p1c, accv, den, saw);

        // remainder chunks (deg > 32; rare for Poisson(16))
        #pragma unroll 1
        for (int p = p0c + 32; p < p1c; p += 16) {
            int e = p + eslot;
            int i = cidx(e, p0c, p1c);
            int s = src_s[i];
            float a = attr_s[i];
            const uint4* kr = (const uint4*)(kvbase + (size_t)s * 128);
            uint4 r0 = kr[0], r1 = kr[1], r2 = kr[2], r3 = kr[3];
            chunk16(r0, r1, r2, r3, qc0, qc1, qc2, qc3,
                    a, qw, e, p1c, accv, den, saw);
        }

        // den/saw: reduce across the 16 edge-lanes of this head
        den += __shfl_xor(den, 1); den += __shfl_xor(den, 2);
        den += __shfl_xor(den, 4); den += __shfl_xor(den, 8);
        saw += __shfl_xor(saw, 1); saw += __shfl_xor(saw, 2);
        saw += __shfl_xor(saw, 4); saw += __shfl_xor(saw, 8);

        // acc transpose: (head,edge) partials -> per-channel totals via LDS
        float4* bw = (float4*)(buf + eslot * 68 + head * 16);
        bw[0] = make_float4(accv[0],  accv[1],  accv[2],  accv[3]);
        bw[1] = make_float4(accv[4],  accv[5],  accv[6],  accv[7]);
        bw[2] = make_float4(accv[8],  accv[9],  accv[10], accv[11]);
        bw[3] = make_float4(accv[12], accv[13], accv[14], accv[15]);
        float tot = 0.f;
        #pragma unroll
        for (int e2 = 0; e2 < 16; ++e2) tot += buf[e2 * 68 + lane];

        float o = fmaf(saw, wec, tot) / (den + 1e-16f) + skc;
        if (do_relu) o = fmaxf(o, 0.f);
        out[(size_t)node * 64 + lane] = o;

        if (do_pool) {
            int b = batch[node];
            atomicAdd(&gsum[(size_t)b * 64 + lane], o);
            if (lane == 0) atomicAdd(&gcnt[b], 1.f);
        }

        // ---- rotate pipeline ----
        node = nx1;
        if (node >= NN) break;
        p0c = p0n; p1c = p1n;
        p0n = p0n2; p1n = p1n2;
        s0c = s0n; a0c = a0n;
        s1c = s1n; a1c = a1n;
        qc0 = qn0; qc1 = qn1; qc2 = qn2; qc3 = qn3;
        skc = skn;
    }
}

// ---------------------------------------------------------------------------
// mean-pool finalize + 3-layer MLP head; one block (128 thr) per graph
// ---------------------------------------------------------------------------
__global__ __launch_bounds__(128) void pool_mlp(
    const float* __restrict__ gsum, const float* __restrict__ gcnt,
    const float* __restrict__ W1, const float* __restrict__ b1,
    const float* __restrict__ W2, const float* __restrict__ b2,
    const float* __restrict__ W3, const float* __restrict__ b3,
    float* __restrict__ out)
{
    __shared__ float g[64];
    __shared__ float h1s[64];
    __shared__ float h2s[16];
    int b = blockIdx.x, t = threadIdx.x;

    if (t < 64) {
        float c = gcnt[b];
        g[t] = gsum[(size_t)b * 64 + t] / fmaxf(c, 1.f);
    }
    __syncthreads();
    if (t < 64) {
        float a = b1[t];
        #pragma unroll
        for (int i = 0; i < 64; ++i) a = fmaf(g[i], W1[i * 64 + t], a);
        h1s[t] = fmaxf(a, 0.f);
    }
    __syncthreads();
    if (t < 16) {
        float a = b2[t];
        #pragma unroll
        for (int i = 0; i < 64; ++i) a = fmaf(h1s[i], W2[i * 16 + t], a);
        h2s[t] = fmaxf(a, 0.f);
    }
    __syncthreads();
    float a = b3[t];
    #pragma unroll
    for (int i = 0; i < 16; ++i) a = fmaf(h2s[i], W3[i * 128 + t], a);
    out[(size_t)b * 128 + t] = a;
}

// ---------------------------------------------------------------------------
extern "C" void kernel_launch(void* const* d_in, const int* in_sizes, int n_in,
                              void* d_out, int out_size, void* d_ws, size_t ws_size,
                              hipStream_t stream) {
    const float* x         = (const float*)d_in[0];
    const float* edge_attr = (const float*)d_in[1];
    const int*   edge_index= (const int*)d_in[2];
    const int*   batch     = (const int*)d_in[3];
    const float* Wq   = (const float*)d_in[4];
    const float* bq   = (const float*)d_in[5];
    const float* Wk   = (const float*)d_in[6];
    const float* bk   = (const float*)d_in[7];
    const float* Wv   = (const float*)d_in[8];
    const float* bv   = (const float*)d_in[9];
    const float* We   = (const float*)d_in[10];
    const float* Wsk  = (const float*)d_in[11];
    const float* bsk  = (const float*)d_in[12];
    const float* W1   = (const float*)d_in[13];
    const float* b1   = (const float*)d_in[14];
    const float* W2   = (const float*)d_in[15];
    const float* b2   = (const float*)d_in[16];
    const float* W3   = (const float*)d_in[17];
    const float* b3   = (const float*)d_in[18];

    float* out        = (float*)d_out;
    float* node_emb   = out;                         // N*64
    float* graph_feat = out + (size_t)NN * 64;       // G*128

    float* wsf    = (float*)d_ws;
    float* q      = wsf;
    float* kvf    = q    + (size_t)NN * 64;          // N*64 dwords: packed half2(k,v)
    float* skp    = kvf  + (size_t)NN * 64;
    float* h      = skp  + (size_t)NN * 64;
    float* attr_s = h    + (size_t)NN * 64;
    int*   src_s  = (int*)(attr_s + EE);
    int*   row_ptr= src_s + EE;
    int*   wpos   = row_ptr + (NN + 1);
    float* gsum   = (float*)(wpos + NN);
    float* gcnt   = gsum + (size_t)GG * 64;
    __half* kvh   = (__half*)kvf;

    // ---- CSR build (dst-sorted edges); reused by all 3 layers ----
    zero_i32<<<(NN + 255) / 256, 256, 0, stream>>>(wpos, NN);
    zero_f32<<<(GG * 64 + GG + 255) / 256, 256, 0, stream>>>(gsum, GG * 64 + GG);
    hist_kernel<<<(EE + 255) / 256, 256, 0, stream>>>(edge_index + EE, wpos);
    scan_kernel<<<1, 1024, 0, stream>>>(wpos, row_ptr, wpos);
    scatter_kernel<<<(EE + 255) / 256, 256, 0, stream>>>(edge_index, edge_attr,
                                                         wpos, src_s, attr_s);

    int gemm_grid = (NN + 31) / 32;

    const float* layer_in = x;
    for (int l = 0; l < LL; ++l) {
        const float* Wq_l = Wq + (size_t)l * 64 * 64;
        const float* Wk_l = Wk + (size_t)l * 64 * 64;
        const float* Wv_l = Wv + (size_t)l * 64 * 64;
        const float* Ws_l = Wsk + (size_t)l * 64 * 64;
        const float* bq_l = bq + (size_t)l * 64;
        const float* bk_l = bk + (size_t)l * 64;
        const float* bv_l = bv + (size_t)l * 64;
        const float* bs_l = bsk + (size_t)l * 64;
        const float* We_l = We + (size_t)l * 64;

        node_gemm<<<gemm_grid, 256, 0, stream>>>(layer_in,
            Wq_l, bq_l, Wk_l, bk_l, Wv_l, bv_l, Ws_l, bs_l,
            q, kvh, skp);

        int last = (l == LL - 1);
        float* dst_h = last ? node_emb : h;
        node_attn<<<ATTN_BLOCKS, 256, 0, stream>>>(q, kvh, skp, We_l,
            row_ptr, src_s, attr_s,
            dst_h, /*relu=*/!last, /*pool=*/last,
            batch, gsum, gcnt);

        layer_in = h;
    }

    pool_mlp<<<GG, 128, 0, stream>>>(gsum, gcnt, W1, b1, W2, b2, W3, b3, graph_feat);
}